// Round 5
// baseline (175.903 us; speedup 1.0000x reference)
//
#include <hip/hip_runtime.h>

// Guided blur (multichannel guided filter), B=8, C=Cp=3, H=W=512, k=5, eps=1e-4.
// SINGLE fused kernel, LDS-free, barrier-free:
//   - wave owns cols: raw reads at x0-2+lane, a-values at cols x0+lane (valid lanes 0..59),
//     final outputs at cols x0+2+lane (valid lanes 0..55) -> 56 output cols/wave
//   - horizontal 5-taps via full-wave __shfl_down log-tree (3 shuffles per channel)
//   - stage 1: vertical 5-row roll of 21 raw-stat channels (ring1 over raw rows)
//       -> per-row hsum5 -> per-pixel symmetric 3x3 solve -> a[9], b[3]
//   - stage 2: hsum5 of a,b immediately; vertical 5-row roll of those 12 (ring2)
//       -> mean_a, mean_b -> combine with guidance -> out
//   Exactness of fusion under reflect padding: box blur at padded position q uses the
//   window multiset {refl(q+d)}, which equals the window multiset at refl(q); a computed
//   on reflected raw windows therefore equals reflect-pad of a. Uniform weights => equal sums.
// No d_ws usage.

namespace {

constexpr int BN = 8;
constexpr int HH = 512;
constexpr int WW = 512;
constexpr int CSZ = HH * WW;
constexpr float GEPS = 1e-4f;
constexpr int OUTW = 56;            // output cols per wave (64 - 2*4 halo)
constexpr int SR   = 16;            // output rows per wave strip
constexpr int ITER = SR + 8;        // raw rows read per strip (two cascaded 5-blurs: +8)
constexpr int WPB  = 2;             // waves per block

__device__ __forceinline__ int refl(int i, int n) {
    // jnp.pad reflect: -1 -> 1, -2 -> 2, n -> n-2, n+1 -> n-3
    if (i < 0) i = -i;
    if (i >= n) i = 2 * n - 2 - i;
    return i;
}

// lane u gets v[u]+v[u+1]+v[u+2]+v[u+3]+v[u+4] (valid for u <= 59).
__device__ __forceinline__ float hsum5(float v) {
    float t = v + __shfl_down(v, 1);   // [u..u+1]
    float q = t + __shfl_down(t, 2);   // [u..u+3]
    return q + __shfl_down(v, 4);      // [u..u+4]
}

__global__ __launch_bounds__(128, 2) void fused_kernel(
        const float* __restrict__ g, const float* __restrict__ p,
        float* __restrict__ out) {
    const int lane = threadIdx.x & 63;
    const int wv   = threadIdx.x >> 6;
    const int x0   = blockIdx.x * OUTW - 2;             // a-col base: a[lane] ~ col x0+lane
    const int yb   = (blockIdx.y * WPB + wv) * SR;
    const int bb   = blockIdx.z;

    const int xr = refl(x0 - 2 + lane, WW);             // raw read col
    const int xo = x0 + 2 + lane;                       // output col
    const int xs = (xo < WW) ? xo : (WW - 1);           // safe col for tail-strip loads
    const bool wr = (lane < OUTW) && (xo < WW);

    const float* gB = g + (size_t)bb * 3 * CSZ;
    const float* pB = p + (size_t)bb * 3 * CSZ;
    float* oB = out + (size_t)bb * 3 * CSZ;

    float V1[21];                       // stage-1 vertical window sums (21 stat channels)
#pragma unroll
    for (int i = 0; i < 21; ++i) V1[i] = 0.f;
    float ring1[5][6];                  // raw rows (6 channels) in the stage-1 window
    float P[3][6];                      // 3-deep raw-row prefetch
    float V2[12];                       // stage-2 vertical sums of hsum'd a,b
#pragma unroll
    for (int i = 0; i < 12; ++i) V2[i] = 0.f;
    float ring2[5][12];                 // hsum'd a,b rows in the stage-2 window

    auto loadrow = [&](int rr, float dst[6]) {
        const int y = refl(yb - 4 + rr, HH);
        const int off = y * WW + xr;
        dst[0] = gB[off]; dst[1] = gB[CSZ + off]; dst[2] = gB[2 * CSZ + off];
        dst[3] = pB[off]; dst[4] = pB[CSZ + off]; dst[5] = pB[2 * CSZ + off];
    };
    auto accum1 = [&](const float c[6], float sgn) {
        float i0 = c[0], i1 = c[1], i2 = c[2], q0 = c[3], q1 = c[4], q2 = c[5];
        float s0 = sgn * i0, s1 = sgn * i1, s2 = sgn * i2;
        V1[0] += s0; V1[1] += s1; V1[2] += s2;
        V1[3] += sgn * q0; V1[4] += sgn * q1; V1[5] += sgn * q2;
        V1[6]  += s0 * i0; V1[7]  += s0 * i1; V1[8]  += s0 * i2;
        V1[9]  += s1 * i1; V1[10] += s1 * i2; V1[11] += s2 * i2;
        V1[12] += s0 * q0; V1[13] += s0 * q1; V1[14] += s0 * q2;
        V1[15] += s1 * q0; V1[16] += s1 * q1; V1[17] += s1 * q2;
        V1[18] += s2 * q0; V1[19] += s2 * q1; V1[20] += s2 * q2;
    };

    loadrow(0, P[0]); loadrow(1, P[1]); loadrow(2, P[2]);

#pragma unroll
    for (int rr = 0; rr < ITER; ++rr) {
        float cur[6];
#pragma unroll
        for (int c = 0; c < 6; ++c) cur[c] = P[rr % 3][c];
        if (rr + 3 < ITER) loadrow(rr + 3, P[rr % 3]);

        // guidance at this iteration's output row (issued early for latency cover)
        float go0 = 0.f, go1 = 0.f, go2 = 0.f;
        int oOff = 0;
        if (rr >= 8) {
            oOff = (yb + rr - 8) * WW + xs;
            go0 = gB[oOff]; go1 = gB[CSZ + oOff]; go2 = gB[2 * CSZ + oOff];
        }

        accum1(cur, 1.f);
        if (rr >= 5) accum1(ring1[rr % 5], -1.f);   // drop raw row rr-5
#pragma unroll
        for (int c = 0; c < 6; ++c) ring1[rr % 5][c] = cur[c];

        if (rr >= 4) {
            // ---- stage 1 finalize: a-row Ay = yb + rr - 6 at col x0+lane ----
            float S[21];
#pragma unroll
            for (int c = 0; c < 21; ++c) S[c] = hsum5(V1[c]);

            const float nrm = 0.04f;  // 1/25
            float mI0 = S[0] * nrm, mI1 = S[1] * nrm, mI2 = S[2] * nrm;
            float mP0 = S[3] * nrm, mP1 = S[4] * nrm, mP2 = S[5] * nrm;
            float v00 = S[6]  * nrm - mI0 * mI0 + GEPS;
            float v01 = S[7]  * nrm - mI0 * mI1;
            float v02 = S[8]  * nrm - mI0 * mI2;
            float v11 = S[9]  * nrm - mI1 * mI1 + GEPS;
            float v12 = S[10] * nrm - mI1 * mI2;
            float v22 = S[11] * nrm - mI2 * mI2 + GEPS;
            float c00 = S[12] * nrm - mI0 * mP0;
            float c01 = S[13] * nrm - mI0 * mP1;
            float c02 = S[14] * nrm - mI0 * mP2;
            float c10 = S[15] * nrm - mI1 * mP0;
            float c11 = S[16] * nrm - mI1 * mP1;
            float c12 = S[17] * nrm - mI1 * mP2;
            float c20 = S[18] * nrm - mI2 * mP0;
            float c21 = S[19] * nrm - mI2 * mP1;
            float c22 = S[20] * nrm - mI2 * mP2;
            // symmetric 3x3 inverse via adjugate (A PD: PSD + eps*I, det >= eps^3 > 0)
            float i00 = v11 * v22 - v12 * v12;
            float i01 = v02 * v12 - v01 * v22;
            float i02 = v01 * v12 - v02 * v11;
            float i11 = v00 * v22 - v02 * v02;
            float i12 = v01 * v02 - v00 * v12;
            float i22 = v00 * v11 - v01 * v01;
            float det = v00 * i00 + v01 * i01 + v02 * i02;
            float rd  = 1.0f / det;
            float a00 = (i00 * c00 + i01 * c10 + i02 * c20) * rd;
            float a01 = (i00 * c01 + i01 * c11 + i02 * c21) * rd;
            float a02 = (i00 * c02 + i01 * c12 + i02 * c22) * rd;
            float a10 = (i01 * c00 + i11 * c10 + i12 * c20) * rd;
            float a11 = (i01 * c01 + i11 * c11 + i12 * c21) * rd;
            float a12 = (i01 * c02 + i11 * c12 + i12 * c22) * rd;
            float a20 = (i02 * c00 + i12 * c10 + i22 * c20) * rd;
            float a21 = (i02 * c01 + i12 * c11 + i22 * c21) * rd;
            float a22 = (i02 * c02 + i12 * c12 + i22 * c22) * rd;
            float b0 = mP0 - (a00 * mI0 + a10 * mI1 + a20 * mI2);
            float b1 = mP1 - (a01 * mI0 + a11 * mI1 + a21 * mI2);
            float b2 = mP2 - (a02 * mI0 + a12 * mI1 + a22 * mI2);

            // ---- stage 2: horizontal 5-tap of a,b now; vertical roll over a-rows ----
            float hv[12];
            hv[0] = hsum5(a00); hv[1] = hsum5(a01); hv[2]  = hsum5(a02);
            hv[3] = hsum5(a10); hv[4] = hsum5(a11); hv[5]  = hsum5(a12);
            hv[6] = hsum5(a20); hv[7] = hsum5(a21); hv[8]  = hsum5(a22);
            hv[9] = hsum5(b0);  hv[10] = hsum5(b1); hv[11] = hsum5(b2);

            const int k2 = (rr - 4) % 5;
#pragma unroll
            for (int c = 0; c < 12; ++c) {
                V2[c] += hv[c];
                if (rr >= 9) V2[c] -= ring2[k2][c];   // drop a-row rr-5 (same slot)
                ring2[k2][c] = hv[c];
            }

            if (rr >= 8) {
                // output row yb + rr - 8, col xo; mean = V2 / 25
                const float n2 = 0.04f;
                float M[12];
#pragma unroll
                for (int c = 0; c < 12; ++c) M[c] = V2[c] * n2;
                float o0 = go0 * M[0] + go1 * M[3] + go2 * M[6] + M[9];
                float o1 = go0 * M[1] + go1 * M[4] + go2 * M[7] + M[10];
                float o2 = go0 * M[2] + go1 * M[5] + go2 * M[8] + M[11];
                if (wr) {
                    oB[oOff]           = o0;
                    oB[CSZ + oOff]     = o1;
                    oB[2 * CSZ + oOff] = o2;
                }
            }
        }
    }
}

}  // namespace

extern "C" void kernel_launch(void* const* d_in, const int* in_sizes, int n_in,
                              void* d_out, int out_size, void* d_ws, size_t ws_size,
                              hipStream_t stream) {
    const float* g  = (const float*)d_in[0];   // guidance [8,3,512,512]
    const float* p  = (const float*)d_in[1];   // input    [8,3,512,512]
    float* out = (float*)d_out;                // [8,3,512,512]

    // 10 col-strips of 56 (last partial), 16 row-groups of 32, 8 batches
    dim3 grid((WW + OUTW - 1) / OUTW, HH / (SR * WPB), BN);   // (10, 16, 8) = 1280 blocks
    dim3 block(WPB * 64);                                      // 128 threads = 2 waves

    hipLaunchKernelGGL(fused_kernel, grid, block, 0, stream, g, p, out);
}

// Round 6
// 140.780 us; speedup vs baseline: 1.2495x; 1.2495x over previous
//
#include <hip/hip_runtime.h>

// Guided blur (multichannel guided filter), B=8, C=Cp=3, H=W=512, k=5, eps=1e-4.
// SINGLE fused kernel, LDS-free, barrier-free, shuffle-free (DPP only):
//   - wave = 4 x 16-lane segments; each segment: 16 raw cols, 12 valid a-cols, 8 output cols
//     (two cascaded 5-tap horizontal blurs each eat a 2-col halo per side)
//   - horizontal 5-taps via v_add + DPP row_shl:{1,2,4} (VALU pipe; zero LDS-pipe traffic)
//   - stage 1: vertical 5-row roll of 21 raw-stat channels -> hsum5 -> symmetric 3x3 solve -> a,b
//   - stage 2: hsum5 of a,b; vertical 5-row roll of those 12 -> combine with guidance -> out
//   - rows processed in trips of 5 with template<int I> expansion: every ring index is a
//     compile-time constant => SROA keeps ring buffers in VGPRs (NO PromoteAlloca-to-LDS,
//     which cost round 5 ~40us of LDS-pipe serialization + 568K bank conflicts)
//   Fusion exactness under reflect padding: window multiset of the padded position equals
//   the window multiset of the reflected position (uniform box weights => equal sums).
// No d_ws usage.

namespace {

constexpr int BN = 8;
constexpr int HH = 512;
constexpr int WW = 512;
constexpr int CSZ = HH * WW;
constexpr float GEPS = 1e-4f;
constexpr int SEGW = 8;             // output cols per 16-lane segment
constexpr int OUTW = 4 * SEGW;      // 32 output cols per wave
constexpr int SR   = 32;            // output rows per wave strip
constexpr int NTRIP = (SR + 8) / 5; // 8 trips x 5 raw rows = 40 rows read

__device__ __forceinline__ int refl(int i, int n) {
    // jnp.pad reflect: -1 -> 1, -2 -> 2, n -> n-2, n+1 -> n-3
    if (i < 0) i = -i;
    if (i >= n) i = 2 * n - 2 - i;
    return i;
}

// DPP row_shl:N within each 16-lane row: lane u receives lane u+N (0 past row end).
template <int N>
__device__ __forceinline__ float shlN(float v) {
    return __builtin_bit_cast(float,
        __builtin_amdgcn_update_dpp(0, __builtin_bit_cast(int, v),
                                    0x100 + N, 0xF, 0xF, true));
}
// row-local lane u gets v[u]+v[u+1]+v[u+2]+v[u+3]+v[u+4]; valid for u <= 11.
__device__ __forceinline__ float hsum5(float v) {
    float t = v + shlN<1>(v);
    float q = t + shlN<2>(t);
    return q + shlN<4>(v);
}

struct St {
    float V1[21];      // stage-1 vertical window sums (21 stat channels)
    float r1[5][6];    // last 5 raw rows (6 channels)
    float V2[12];      // stage-2 vertical sums of hsum'd a,b
    float r2[5][12];   // last 5 hsum'd a,b rows
};

struct Ctx {
    const float *g0, *g1, *g2, *p0, *p1, *p2;  // channel base pointers
    float *o0, *o1, *o2;
    int yb, xr, xs;
    bool wr;
};

// One raw row. rr = 5*t + I. Ring slots use constexpr I ((5t+I)%5 == I).
template <int I, bool SUB1, bool SOLVE, bool V2SUB, bool OUT>
__device__ __forceinline__ void row(St& st, const Ctx& cx, int t) {
    const int rr = 5 * t + I;
    const int y = refl(cx.yb - 4 + rr, HH);
    const int off = y * WW + cx.xr;
    float c0 = cx.g0[off], c1 = cx.g1[off], c2 = cx.g2[off];
    float c3 = cx.p0[off], c4 = cx.p1[off], c5 = cx.p2[off];

    // add current raw row
    st.V1[0] += c0; st.V1[1] += c1; st.V1[2] += c2;
    st.V1[3] += c3; st.V1[4] += c4; st.V1[5] += c5;
    st.V1[6]  += c0 * c0; st.V1[7]  += c0 * c1; st.V1[8]  += c0 * c2;
    st.V1[9]  += c1 * c1; st.V1[10] += c1 * c2; st.V1[11] += c2 * c2;
    st.V1[12] += c0 * c3; st.V1[13] += c0 * c4; st.V1[14] += c0 * c5;
    st.V1[15] += c1 * c3; st.V1[16] += c1 * c4; st.V1[17] += c1 * c5;
    st.V1[18] += c2 * c3; st.V1[19] += c2 * c4; st.V1[20] += c2 * c5;

    if constexpr (SUB1) {   // drop raw row rr-5 (same constexpr slot I)
        float o0 = st.r1[I][0], o1 = st.r1[I][1], o2 = st.r1[I][2];
        float o3 = st.r1[I][3], o4 = st.r1[I][4], o5 = st.r1[I][5];
        st.V1[0] -= o0; st.V1[1] -= o1; st.V1[2] -= o2;
        st.V1[3] -= o3; st.V1[4] -= o4; st.V1[5] -= o5;
        st.V1[6]  -= o0 * o0; st.V1[7]  -= o0 * o1; st.V1[8]  -= o0 * o2;
        st.V1[9]  -= o1 * o1; st.V1[10] -= o1 * o2; st.V1[11] -= o2 * o2;
        st.V1[12] -= o0 * o3; st.V1[13] -= o0 * o4; st.V1[14] -= o0 * o5;
        st.V1[15] -= o1 * o3; st.V1[16] -= o1 * o4; st.V1[17] -= o1 * o5;
        st.V1[18] -= o2 * o3; st.V1[19] -= o2 * o4; st.V1[20] -= o2 * o5;
    }
    st.r1[I][0] = c0; st.r1[I][1] = c1; st.r1[I][2] = c2;
    st.r1[I][3] = c3; st.r1[I][4] = c4; st.r1[I][5] = c5;

    if constexpr (SOLVE) {
        // ---- stage 1 finalize: a-row at y = yb + rr - 6, col xbase+l ----
        float S[21];
#pragma unroll
        for (int c = 0; c < 21; ++c) S[c] = hsum5(st.V1[c]);

        const float nrm = 0.04f;  // 1/25
        float mI0 = S[0] * nrm, mI1 = S[1] * nrm, mI2 = S[2] * nrm;
        float mP0 = S[3] * nrm, mP1 = S[4] * nrm, mP2 = S[5] * nrm;
        float v00 = S[6]  * nrm - mI0 * mI0 + GEPS;
        float v01 = S[7]  * nrm - mI0 * mI1;
        float v02 = S[8]  * nrm - mI0 * mI2;
        float v11 = S[9]  * nrm - mI1 * mI1 + GEPS;
        float v12 = S[10] * nrm - mI1 * mI2;
        float v22 = S[11] * nrm - mI2 * mI2 + GEPS;
        float c00 = S[12] * nrm - mI0 * mP0;
        float c01 = S[13] * nrm - mI0 * mP1;
        float c02 = S[14] * nrm - mI0 * mP2;
        float c10 = S[15] * nrm - mI1 * mP0;
        float c11 = S[16] * nrm - mI1 * mP1;
        float c12 = S[17] * nrm - mI1 * mP2;
        float c20 = S[18] * nrm - mI2 * mP0;
        float c21 = S[19] * nrm - mI2 * mP1;
        float c22 = S[20] * nrm - mI2 * mP2;
        // symmetric 3x3 inverse via adjugate (A PD: PSD + eps*I)
        float i00 = v11 * v22 - v12 * v12;
        float i01 = v02 * v12 - v01 * v22;
        float i02 = v01 * v12 - v02 * v11;
        float i11 = v00 * v22 - v02 * v02;
        float i12 = v01 * v02 - v00 * v12;
        float i22 = v00 * v11 - v01 * v01;
        float det = v00 * i00 + v01 * i01 + v02 * i02;
        float rd  = 1.0f / det;
        float a00 = (i00 * c00 + i01 * c10 + i02 * c20) * rd;
        float a01 = (i00 * c01 + i01 * c11 + i02 * c21) * rd;
        float a02 = (i00 * c02 + i01 * c12 + i02 * c22) * rd;
        float a10 = (i01 * c00 + i11 * c10 + i12 * c20) * rd;
        float a11 = (i01 * c01 + i11 * c11 + i12 * c21) * rd;
        float a12 = (i01 * c02 + i11 * c12 + i12 * c22) * rd;
        float a20 = (i02 * c00 + i12 * c10 + i22 * c20) * rd;
        float a21 = (i02 * c01 + i12 * c11 + i22 * c21) * rd;
        float a22 = (i02 * c02 + i12 * c12 + i22 * c22) * rd;
        float b0 = mP0 - (a00 * mI0 + a10 * mI1 + a20 * mI2);
        float b1 = mP1 - (a01 * mI0 + a11 * mI1 + a21 * mI2);
        float b2 = mP2 - (a02 * mI0 + a12 * mI1 + a22 * mI2);

        // ---- stage 2: horizontal 5-tap of a,b now; vertical roll ----
        float hv[12];
        hv[0] = hsum5(a00); hv[1]  = hsum5(a01); hv[2]  = hsum5(a02);
        hv[3] = hsum5(a10); hv[4]  = hsum5(a11); hv[5]  = hsum5(a12);
        hv[6] = hsum5(a20); hv[7]  = hsum5(a21); hv[8]  = hsum5(a22);
        hv[9] = hsum5(b0);  hv[10] = hsum5(b1);  hv[11] = hsum5(b2);

#pragma unroll
        for (int c = 0; c < 12; ++c) {
            st.V2[c] += hv[c];
            if constexpr (V2SUB) st.V2[c] -= st.r2[I][c];  // read old before overwrite
            st.r2[I][c] = hv[c];
        }

        if constexpr (OUT) {
            // output row yo = yb + rr - 8, col xo; mean = V2 / 25
            const int yo = cx.yb + rr - 8;
            const int o = yo * WW + cx.xs;
            float g0 = cx.g0[o], g1 = cx.g1[o], g2 = cx.g2[o];
            float M[12];
#pragma unroll
            for (int c = 0; c < 12; ++c) M[c] = st.V2[c] * 0.04f;
            float o0 = g0 * M[0] + g1 * M[3] + g2 * M[6] + M[9];
            float o1 = g0 * M[1] + g1 * M[4] + g2 * M[7] + M[10];
            float o2 = g0 * M[2] + g1 * M[5] + g2 * M[8] + M[11];
            if (cx.wr) {
                cx.o0[o] = o0;
                cx.o1[o] = o1;
                cx.o2[o] = o2;
            }
        }
    }
}

__global__ __launch_bounds__(64, 2) void fused_kernel(
        const float* __restrict__ g, const float* __restrict__ p,
        float* __restrict__ out) {
    const int lane = threadIdx.x;       // 64 threads = 1 wave
    const int l    = lane & 15;
    const int seg  = lane >> 4;
    const int XO   = blockIdx.x * OUTW;
    const int bb   = blockIdx.z;

    const int xbase = XO + seg * SEGW - 2;          // a-col of row-local lane 0
    const int xrq   = xbase + l - 2;                // raw read col (pre-reflect)
    const int xo    = xbase + l + 2;                // output col (valid l < SEGW)

    Ctx cx;
    cx.g0 = g + (size_t)bb * 3 * CSZ; cx.g1 = cx.g0 + CSZ; cx.g2 = cx.g0 + 2 * CSZ;
    cx.p0 = p + (size_t)bb * 3 * CSZ; cx.p1 = cx.p0 + CSZ; cx.p2 = cx.p0 + 2 * CSZ;
    cx.o0 = out + (size_t)bb * 3 * CSZ; cx.o1 = cx.o0 + CSZ; cx.o2 = cx.o0 + 2 * CSZ;
    cx.yb = blockIdx.y * SR;
    cx.xr = refl(xrq, WW);
    cx.xs = (xo < WW) ? xo : (WW - 1);
    cx.wr = (l < SEGW);                              // xo < 512 guaranteed for l < SEGW

    St st;
#pragma unroll
    for (int i = 0; i < 21; ++i) st.V1[i] = 0.f;
#pragma unroll
    for (int i = 0; i < 12; ++i) st.V2[i] = 0.f;

    // trip 0: rows 0..4 — accumulate only; first solve at rr=4
    row<0, false, false, false, false>(st, cx, 0);
    row<1, false, false, false, false>(st, cx, 0);
    row<2, false, false, false, false>(st, cx, 0);
    row<3, false, false, false, false>(st, cx, 0);
    row<4, false, true,  false, false>(st, cx, 0);
    // trip 1: rows 5..9 — subtract+solve; first outputs at rr=8,9; first V2-sub at rr=9
    row<0, true, true, false, false>(st, cx, 1);
    row<1, true, true, false, false>(st, cx, 1);
    row<2, true, true, false, false>(st, cx, 1);
    row<3, true, true, false, true >(st, cx, 1);
    row<4, true, true, true,  true >(st, cx, 1);
    // steady trips: everything on
#pragma unroll 1
    for (int t = 2; t < NTRIP; ++t) {
        row<0, true, true, true, true>(st, cx, t);
        row<1, true, true, true, true>(st, cx, t);
        row<2, true, true, true, true>(st, cx, t);
        row<3, true, true, true, true>(st, cx, t);
        row<4, true, true, true, true>(st, cx, t);
    }
}

}  // namespace

extern "C" void kernel_launch(void* const* d_in, const int* in_sizes, int n_in,
                              void* d_out, int out_size, void* d_ws, size_t ws_size,
                              hipStream_t stream) {
    const float* g  = (const float*)d_in[0];   // guidance [8,3,512,512]
    const float* p  = (const float*)d_in[1];   // input    [8,3,512,512]
    float* out = (float*)d_out;                // [8,3,512,512]

    dim3 grid(WW / OUTW, HH / SR, BN);         // (16, 16, 8) = 2048 blocks
    dim3 block(64);                            // 1 wave per block

    hipLaunchKernelGGL(fused_kernel, grid, block, 0, stream, g, p, out);
}